// Round 5
// baseline (271.801 us; speedup 1.0000x reference)
//
#include <hip/hip_runtime.h>

// Predictor: MLP3 (Linear+BN(train)+ReLU x2, Linear) -> LSTM(64), 1 cond + 25 self-feed steps.
// B=16384, OUT=128 (x3 -> 384), HID=32, LSTM_H=64, NPRED=25. Output (B,25,64) fp32.
// All GEMMs via split-precision bf16 MFMA: P = A_hi*B_hi + A_hi*B_lo + A_lo*B_hi (fp32 accum).
// BN stats BIT-DETERMINISTIC (slot partials + fixed-order reduce; float atomics diverge replays).
// k_lstm: 32-row blocks (R2-proven), 4 blocks/CU, coalesced out-stores via fp32 LDS dbuf.

#define EPSV 1e-5f

typedef __attribute__((ext_vector_type(8))) short bf16x8;
typedef __attribute__((ext_vector_type(4))) float f32x4;

__device__ __forceinline__ float rcp_f(float x) { return __builtin_amdgcn_rcpf(x); }
__device__ __forceinline__ float sigm(float x) { return rcp_f(1.f + __expf(-x)); }
__device__ __forceinline__ float tanh_fast(float x) {
    return 1.f - 2.f * rcp_f(__expf(2.f * x) + 1.f);  // saturates correctly at +-1
}
__device__ __forceinline__ void split_bf16(float x, ushort& hi, ushort& lo) {
    unsigned xb = __builtin_bit_cast(unsigned, x);
    hi = (ushort)(xb >> 16);
    float hif = __builtin_bit_cast(float, xb & 0xffff0000u);
    unsigned lb = __builtin_bit_cast(unsigned, x - hif);
    lo = (ushort)(lb >> 16);
}

// ---------------- kernel 0: split Wih/Wsum/W1/W2 into bf16 hi/lo; bsum ----------------
__global__ __launch_bounds__(256) void k_prep(
    const float* __restrict__ Wih, const float* __restrict__ Whh,
    const float* __restrict__ bih, const float* __restrict__ bhh,
    const float* __restrict__ W1, const float* __restrict__ W2,
    ushort* __restrict__ Wih_hi, ushort* __restrict__ Wih_lo,
    ushort* __restrict__ Wsum_hi, ushort* __restrict__ Wsum_lo,
    ushort* __restrict__ W1hi, ushort* __restrict__ W1lo,
    ushort* __restrict__ W2hi, ushort* __restrict__ W2lo,
    float* __restrict__ bsum)
{
    int i = blockIdx.x * 256 + threadIdx.x;
    ushort h, l;
    if (i < 16384) {
        float wi = Wih[i];
        float wsv = wi + Whh[i];
        split_bf16(wi, h, l);  Wih_hi[i] = h;  Wih_lo[i] = l;
        split_bf16(wsv, h, l); Wsum_hi[i] = h; Wsum_lo[i] = l;
    }
    if (i < 12288) { split_bf16(W1[i], h, l); W1hi[i] = h; W1lo[i] = l; }
    if (i < 1024)  { split_bf16(W2[i], h, l); W2hi[i] = h; W2lo[i] = l; }
    if (i < 256)   bsum[i] = bih[i] + bhh[i];
}

// ---------------- k_red: fixed-order BN-stats reduce -> scale/shift (deterministic) ----------------
__global__ __launch_bounds__(256) void k_red(const float* __restrict__ part,
                                             const float* __restrict__ g,
                                             const float* __restrict__ be,
                                             float* __restrict__ scsh) {
    __shared__ float rs[8][32], rq[8][32];
    const int t = threadIdx.x, ch = t & 31, sl = t >> 5;
    float s = 0.f, q = 0.f;
    #pragma unroll 4
    for (int i = 0; i < 128; ++i) {
        int b = sl * 128 + i;
        s += part[b * 32 + ch];
        q += part[32768 + b * 32 + ch];
    }
    rs[sl][ch] = s; rq[sl][ch] = q;
    __syncthreads();
    if (t < 32) {
        float ss = 0.f, qq = 0.f;
        #pragma unroll
        for (int k = 0; k < 8; ++k) { ss += rs[k][t]; qq += rq[k][t]; }
        float mu = ss * (1.f / 16384.f);
        float va = qq * (1.f / 16384.f) - mu * mu;
        float sc = g[t] * rsqrtf(va + EPSV);
        scsh[t] = sc; scsh[32 + t] = be[t] - mu * sc;
    }
}

// ---------------- kernel 1: pre = [x0|x1|x2] @ W1^T + b1 (MFMA), + BN1 partial stats ----------------
__global__ __launch_bounds__(256) void k_mlp1(
    const float* __restrict__ x0, const float* __restrict__ x1, const float* __restrict__ x2,
    const ushort* __restrict__ W1hi, const ushort* __restrict__ W1lo,
    const float* __restrict__ b1,
    float* __restrict__ pre, float* __restrict__ st1p)
{
    __shared__ __align__(16) ushort xhi[32 * 392];
    __shared__ __align__(16) ushort xlo[32 * 392];
    const int tid = threadIdx.x;
    const int r0  = blockIdx.x * 32;

    for (int a = 0; a < 3; ++a) {
        const float* xp = (a == 0) ? x0 : (a == 1) ? x1 : x2;
        const float4* src = (const float4*)(xp + (size_t)r0 * 128);
        #pragma unroll
        for (int it = 0; it < 4; ++it) {
            int i = it * 256 + tid;
            int row = i >> 5, c4 = i & 31;
            float4 v = src[i];
            ushort h0, l0, h1, l1, h2, l2, h3, l3;
            split_bf16(v.x, h0, l0); split_bf16(v.y, h1, l1);
            split_bf16(v.z, h2, l2); split_bf16(v.w, h3, l3);
            int ofs = row * 392 + a * 128 + c4 * 4;
            *(ushort4*)&xhi[ofs] = make_ushort4(h0, h1, h2, h3);
            *(ushort4*)&xlo[ofs] = make_ushort4(l0, l1, l2, l3);
        }
    }
    __syncthreads();

    const int lane = tid & 63, l15 = lane & 15, lg = lane >> 4, q = tid >> 6;
    const int m0 = (q & 1) * 16, n0 = (q >> 1) * 16;
    const float bias = b1[n0 + l15];
    f32x4 acc = {bias, bias, bias, bias};
    #pragma unroll
    for (int kt = 0; kt < 12; ++kt) {
        bf16x8 ahi = *(const bf16x8*)&xhi[(m0 + l15) * 392 + kt * 32 + lg * 8];
        bf16x8 alo = *(const bf16x8*)&xlo[(m0 + l15) * 392 + kt * 32 + lg * 8];
        bf16x8 bhi = *(const bf16x8*)(W1hi + (size_t)(n0 + l15) * 384 + kt * 32 + lg * 8);
        bf16x8 blo = *(const bf16x8*)(W1lo + (size_t)(n0 + l15) * 384 + kt * 32 + lg * 8);
        acc = __builtin_amdgcn_mfma_f32_16x16x32_bf16(ahi, bhi, acc, 0, 0, 0);
        acc = __builtin_amdgcn_mfma_f32_16x16x32_bf16(ahi, blo, acc, 0, 0, 0);
        acc = __builtin_amdgcn_mfma_f32_16x16x32_bf16(alo, bhi, acc, 0, 0, 0);
    }
    #pragma unroll
    for (int rg = 0; rg < 4; ++rg)
        pre[(size_t)(r0 + m0 + lg * 4 + rg) * 32 + n0 + l15] = acc[rg];
    float s  = (acc[0] + acc[1]) + (acc[2] + acc[3]);
    float sq = (acc[0] * acc[0] + acc[1] * acc[1]) + (acc[2] * acc[2] + acc[3] * acc[3]);
    s  += __shfl_xor(s, 16);  s  += __shfl_xor(s, 32);
    sq += __shfl_xor(sq, 16); sq += __shfl_xor(sq, 32);
    if (lg == 0) {
        int slot = (blockIdx.x * 2 + (q & 1)) * 32 + n0 + l15;
        st1p[slot] = s;
        st1p[32768 + slot] = sq;
    }
}

// ---------------- kernel 2: h1 = relu(BN1(pre)); pre = h1 @ W2^T + b2 IN-PLACE; BN2 partials ----------------
__global__ __launch_bounds__(256) void k_mlp2(
    float* __restrict__ pre, const float* __restrict__ scsh1,
    const ushort* __restrict__ W2hi, const ushort* __restrict__ W2lo,
    const float* __restrict__ b2, float* __restrict__ st2p)
{
    __shared__ __align__(16) ushort hhi[32 * 40];
    __shared__ __align__(16) ushort hlo[32 * 40];
    __shared__ float bnsc[32], bnsh[32];
    const int tid = threadIdx.x;
    const int r0  = blockIdx.x * 32;

    if (tid < 32) { bnsc[tid] = scsh1[tid]; bnsh[tid] = scsh1[32 + tid]; }
    __syncthreads();
    {
        int row = tid >> 3, c4 = tid & 7;
        float4 v = ((const float4*)(pre + (size_t)r0 * 32))[tid];
        float e0 = fmaxf(fmaf(v.x, bnsc[c4 * 4 + 0], bnsh[c4 * 4 + 0]), 0.f);
        float e1 = fmaxf(fmaf(v.y, bnsc[c4 * 4 + 1], bnsh[c4 * 4 + 1]), 0.f);
        float e2 = fmaxf(fmaf(v.z, bnsc[c4 * 4 + 2], bnsh[c4 * 4 + 2]), 0.f);
        float e3 = fmaxf(fmaf(v.w, bnsc[c4 * 4 + 3], bnsh[c4 * 4 + 3]), 0.f);
        ushort h0, l0, h1, l1, h2, l2, h3, l3;
        split_bf16(e0, h0, l0); split_bf16(e1, h1, l1);
        split_bf16(e2, h2, l2); split_bf16(e3, h3, l3);
        int ofs = row * 40 + c4 * 4;
        *(ushort4*)&hhi[ofs] = make_ushort4(h0, h1, h2, h3);
        *(ushort4*)&hlo[ofs] = make_ushort4(l0, l1, l2, l3);
    }
    __syncthreads();

    const int lane = tid & 63, l15 = lane & 15, lg = lane >> 4, q = tid >> 6;
    const int m0 = (q & 1) * 16, n0 = (q >> 1) * 16;
    const float bias = b2[n0 + l15];
    f32x4 acc = {bias, bias, bias, bias};
    bf16x8 ahi = *(const bf16x8*)&hhi[(m0 + l15) * 40 + lg * 8];
    bf16x8 alo = *(const bf16x8*)&hlo[(m0 + l15) * 40 + lg * 8];
    bf16x8 bhi = *(const bf16x8*)(W2hi + (size_t)(n0 + l15) * 32 + lg * 8);
    bf16x8 blo = *(const bf16x8*)(W2lo + (size_t)(n0 + l15) * 32 + lg * 8);
    acc = __builtin_amdgcn_mfma_f32_16x16x32_bf16(ahi, bhi, acc, 0, 0, 0);
    acc = __builtin_amdgcn_mfma_f32_16x16x32_bf16(ahi, blo, acc, 0, 0, 0);
    acc = __builtin_amdgcn_mfma_f32_16x16x32_bf16(alo, bhi, acc, 0, 0, 0);

    #pragma unroll
    for (int rg = 0; rg < 4; ++rg)
        pre[(size_t)(r0 + m0 + lg * 4 + rg) * 32 + n0 + l15] = acc[rg];
    float s  = (acc[0] + acc[1]) + (acc[2] + acc[3]);
    float sq = (acc[0] * acc[0] + acc[1] * acc[1]) + (acc[2] * acc[2] + acc[3] * acc[3]);
    s  += __shfl_xor(s, 16);  s  += __shfl_xor(s, 32);
    sq += __shfl_xor(sq, 16); sq += __shfl_xor(sq, 32);
    if (lg == 0) {
        int slot = (blockIdx.x * 2 + (q & 1)) * 32 + n0 + l15;
        st2p[slot] = s;
        st2p[32768 + slot] = sq;
    }
}

// ---------------- kernel 3: BN2 -> ReLU -> m = h2@W3^T+b3 -> 26-step LSTM via MFMA ----------------
// 512 blocks x 256 thr; block = 32 rows; 4 blocks/CU. Wave q owns u-block [16q,16q+16).
// h exchanged via dbuf LDS (bf16 hi/lo for MFMA A, fp32 for coalesced out-store); 1 barrier/step.
__global__ __launch_bounds__(256, 4) void k_lstm(
    const float* __restrict__ pre, const float* __restrict__ scsh2,
    const float* __restrict__ W3, const float* __restrict__ b3,
    const ushort* __restrict__ Wih_hi, const ushort* __restrict__ Wih_lo,
    const ushort* __restrict__ Wsum_hi, const ushort* __restrict__ Wsum_lo,
    const float* __restrict__ bsum, float* __restrict__ out)
{
    __shared__ __align__(16) ushort hhi[2][32][72];
    __shared__ __align__(16) ushort hlo[2][32][72];
    __shared__ __align__(16) float hf32[2][32][68];
    __shared__ float bn2sc[32], bn2sh[32];
    const int tid  = threadIdx.x;
    const int lane = tid & 63, l15 = lane & 15, lg = lane >> 4, q = tid >> 6;
    const int r0   = blockIdx.x * 32;

    if (tid < 32) { bn2sc[tid] = scsh2[tid]; bn2sh[tid] = scsh2[32 + tid]; }
    __syncthreads();

    // ---- MLP tail: m = relu(BN2(pre)) @ W3^T + b3; thread (row=tid&31, seg=tid>>5) -> 8 u
    {
        const int row = tid & 31, seg = tid >> 5;
        float h2[32];
        const float4* pr = (const float4*)(pre + (size_t)(r0 + row) * 32);
        #pragma unroll
        for (int j4 = 0; j4 < 8; ++j4) {
            float4 v = pr[j4];
            h2[j4 * 4 + 0] = v.x; h2[j4 * 4 + 1] = v.y;
            h2[j4 * 4 + 2] = v.z; h2[j4 * 4 + 3] = v.w;
        }
        #pragma unroll
        for (int j = 0; j < 32; ++j) h2[j] = fmaxf(fmaf(h2[j], bn2sc[j], bn2sh[j]), 0.f);
        #pragma unroll
        for (int uu = 0; uu < 8; ++uu) {
            int u = seg * 8 + uu;
            const float* w = W3 + u * 32;
            float a0 = 0.f, a1 = 0.f, a2 = 0.f, a3 = 0.f;
            #pragma unroll
            for (int k = 0; k < 32; k += 4) {
                a0 = fmaf(h2[k + 0], w[k + 0], a0);
                a1 = fmaf(h2[k + 1], w[k + 1], a1);
                a2 = fmaf(h2[k + 2], w[k + 2], a2);
                a3 = fmaf(h2[k + 3], w[k + 3], a3);
            }
            float m = b3[u] + ((a0 + a1) + (a2 + a3));
            ushort mh, ml; split_bf16(m, mh, ml);
            hhi[0][row][u] = mh;
            hlo[0][row][u] = ml;
        }
    }

    float bias[4];
    #pragma unroll
    for (int nt = 0; nt < 4; ++nt) bias[nt] = bsum[nt * 64 + q * 16 + l15];
    float c[2][4];
    #pragma unroll
    for (int mt = 0; mt < 2; ++mt)
        #pragma unroll
        for (int rg = 0; rg < 4; ++rg) c[mt][rg] = 0.f;

    bf16x8 Bhi[4][2], Blo[4][2];
    const size_t wofs = (size_t)(q * 16 + l15) * 64 + lg * 8;
    #pragma unroll
    for (int nt = 0; nt < 4; ++nt)
        #pragma unroll
        for (int kt = 0; kt < 2; ++kt) {
            Bhi[nt][kt] = *(const bf16x8*)(Wih_hi + (size_t)nt * 4096 + wofs + kt * 32);
            Blo[nt][kt] = *(const bf16x8*)(Wih_lo + (size_t)nt * 4096 + wofs + kt * 32);
        }
    __syncthreads();

    #pragma unroll 1
    for (int s = 0; s <= 25; ++s) {
        const int buf = s & 1, nbuf = buf ^ 1;

        // ---- coalesced store of h^s (fp32, written during step s-1) -> out slot s-2
        if (s >= 2) {
            #pragma unroll
            for (int it = 0; it < 2; ++it) {
                int fi = it * 256 + tid;        // 0..511 float4s
                int row = fi >> 4, c4 = fi & 15;
                float4 v = *(const float4*)&hf32[buf][row][c4 * 4];
                *(float4*)&out[(size_t)(r0 + row) * 1600 + (size_t)(s - 2) * 64 + c4 * 4] = v;
            }
        }

        f32x4 acc[2][4];
        #pragma unroll
        for (int mt = 0; mt < 2; ++mt)
            #pragma unroll
            for (int nt = 0; nt < 4; ++nt)
                acc[mt][nt] = (f32x4){bias[nt], bias[nt], bias[nt], bias[nt]};

        #pragma unroll
        for (int mt = 0; mt < 2; ++mt) {
            #pragma unroll
            for (int kt = 0; kt < 2; ++kt) {
                bf16x8 ahi = *(const bf16x8*)&hhi[buf][mt * 16 + l15][kt * 32 + lg * 8];
                bf16x8 alo = *(const bf16x8*)&hlo[buf][mt * 16 + l15][kt * 32 + lg * 8];
                #pragma unroll
                for (int nt = 0; nt < 4; ++nt) {
                    acc[mt][nt] = __builtin_amdgcn_mfma_f32_16x16x32_bf16(ahi, Bhi[nt][kt], acc[mt][nt], 0, 0, 0);
                    acc[mt][nt] = __builtin_amdgcn_mfma_f32_16x16x32_bf16(ahi, Blo[nt][kt], acc[mt][nt], 0, 0, 0);
                    acc[mt][nt] = __builtin_amdgcn_mfma_f32_16x16x32_bf16(alo, Bhi[nt][kt], acc[mt][nt], 0, 0, 0);
                }
            }
        }

        // ---- activations; D layout: col=l15 (-> u), row = mt*16 + lg*4 + rg
        const int u = q * 16 + l15;
        #pragma unroll
        for (int mt = 0; mt < 2; ++mt) {
            #pragma unroll
            for (int rg = 0; rg < 4; ++rg) {
                int row = mt * 16 + lg * 4 + rg;
                float iv = acc[mt][0][rg], fv = acc[mt][1][rg];
                float gv = acc[mt][2][rg], ov = acc[mt][3][rg];
                float cc = sigm(fv) * c[mt][rg] + sigm(iv) * tanh_fast(gv);
                c[mt][rg] = cc;
                float hn = sigm(ov) * tanh_fast(cc);
                ushort hh, hl; split_bf16(hn, hh, hl);
                hhi[nbuf][row][u] = hh;
                hlo[nbuf][row][u] = hl;
                hf32[nbuf][row][u] = hn;
            }
        }

        if (s == 0) {
            #pragma unroll
            for (int nt = 0; nt < 4; ++nt)
                #pragma unroll
                for (int kt = 0; kt < 2; ++kt) {
                    Bhi[nt][kt] = *(const bf16x8*)(Wsum_hi + (size_t)nt * 4096 + wofs + kt * 32);
                    Blo[nt][kt] = *(const bf16x8*)(Wsum_lo + (size_t)nt * 4096 + wofs + kt * 32);
                }
        }
        __syncthreads();
    }

    // ---- epilogue: store h^26 -> out slot 24 (in hf32[0], written at s=25)
    #pragma unroll
    for (int it = 0; it < 2; ++it) {
        int fi = it * 256 + tid;
        int row = fi >> 4, c4 = fi & 15;
        float4 v = *(const float4*)&hf32[0][row][c4 * 4];
        *(float4*)&out[(size_t)(r0 + row) * 1600 + (size_t)24 * 64 + c4 * 4] = v;
    }
}

extern "C" void kernel_launch(void* const* d_in, const int* in_sizes, int n_in,
                              void* d_out, int out_size, void* d_ws, size_t ws_size,
                              hipStream_t stream) {
    const float* x0   = (const float*)d_in[0];
    const float* x1   = (const float*)d_in[1];
    const float* x2   = (const float*)d_in[2];
    const float* W1   = (const float*)d_in[3];
    const float* b1   = (const float*)d_in[4];
    const float* g1   = (const float*)d_in[5];
    const float* be1  = (const float*)d_in[6];
    const float* W2   = (const float*)d_in[7];
    const float* b2   = (const float*)d_in[8];
    const float* g2   = (const float*)d_in[9];
    const float* be2  = (const float*)d_in[10];
    const float* W3   = (const float*)d_in[11];
    const float* b3   = (const float*)d_in[12];
    const float* Wih  = (const float*)d_in[13];
    const float* Whh  = (const float*)d_in[14];
    const float* bih  = (const float*)d_in[15];
    const float* bhh  = (const float*)d_in[16];

    float* ws    = (float*)d_ws;
    float* pre   = ws;                   // 524288 floats (pre1, then pre2 in-place)
    float* st1p  = ws + 524288;          // 65536
    float* st2p  = ws + 589824;          // 65536
    float* scsh1 = ws + 655360;          // 64
    float* scsh2 = ws + 655424;          // 64
    float* bsum  = ws + 655488;          // 256
    ushort* ub   = (ushort*)(ws + 655744);
    ushort* Wih_hi  = ub;                // 16384
    ushort* Wih_lo  = ub + 16384;
    ushort* Wsum_hi = ub + 32768;
    ushort* Wsum_lo = ub + 49152;
    ushort* W1hi    = ub + 65536;        // 12288
    ushort* W1lo    = ub + 77824;
    ushort* W2hi    = ub + 90112;        // 1024
    ushort* W2lo    = ub + 91136;        // end 92160

    hipLaunchKernelGGL(k_prep, dim3(64), dim3(256), 0, stream,
                       Wih, Whh, bih, bhh, W1, W2,
                       Wih_hi, Wih_lo, Wsum_hi, Wsum_lo, W1hi, W1lo, W2hi, W2lo, bsum);
    hipLaunchKernelGGL(k_mlp1, dim3(512), dim3(256), 0, stream,
                       x0, x1, x2, W1hi, W1lo, b1, pre, st1p);
    hipLaunchKernelGGL(k_red, dim3(1), dim3(256), 0, stream, st1p, g1, be1, scsh1);
    hipLaunchKernelGGL(k_mlp2, dim3(512), dim3(256), 0, stream,
                       pre, scsh1, W2hi, W2lo, b2, st2p);
    hipLaunchKernelGGL(k_red, dim3(1), dim3(256), 0, stream, st2p, g2, be2, scsh2);
    hipLaunchKernelGGL(k_lstm, dim3(512), dim3(256), 0, stream,
                       pre, scsh2, W3, b3,
                       Wih_hi, Wih_lo, Wsum_hi, Wsum_lo, bsum, (float*)d_out);
}

// Round 6
// 109.560 us; speedup vs baseline: 2.4808x; 2.4808x over previous
//
#include <hip/hip_runtime.h>

// Predictor: MLP3 (Linear+BN(train)+ReLU x2, Linear) -> LSTM(64), 1 cond + 25 self-feed steps.
// B=16384, OUT=128 (x3 -> 384), HID=32, LSTM_H=64, NPRED=25. Output (B,25,64) fp32.
// All GEMMs via split-precision bf16 MFMA: P = A_hi*B_hi + A_hi*B_lo + A_lo*B_hi (fp32 accum).
// BN stats BIT-DETERMINISTIC (slot partials + fixed-order reduce; float atomics diverge replays).
// k_lstm: 16-row blocks x 1024 (4 blocks/CU), weights resident in VGPRs.
// NOTE: never use __launch_bounds__ min-waves >= 4 here -- it caps VGPR at 64 and spills the
// resident weights to scratch (R4/R5: FETCH 470MB, 3x slowdown). (256,2) -> ~100 VGPR, no spill.

#define EPSV 1e-5f

typedef __attribute__((ext_vector_type(8))) short bf16x8;
typedef __attribute__((ext_vector_type(4))) float f32x4;

__device__ __forceinline__ float rcp_f(float x) { return __builtin_amdgcn_rcpf(x); }
__device__ __forceinline__ float sigm(float x) { return rcp_f(1.f + __expf(-x)); }
__device__ __forceinline__ float tanh_fast(float x) {
    return 1.f - 2.f * rcp_f(__expf(2.f * x) + 1.f);  // saturates correctly at +-1
}
__device__ __forceinline__ void split_bf16(float x, ushort& hi, ushort& lo) {
    unsigned xb = __builtin_bit_cast(unsigned, x);
    hi = (ushort)(xb >> 16);
    float hif = __builtin_bit_cast(float, xb & 0xffff0000u);
    unsigned lb = __builtin_bit_cast(unsigned, x - hif);
    lo = (ushort)(lb >> 16);
}

// ---------------- kernel 0: split Wih/Wsum/W1/W2 into bf16 hi/lo; bsum ----------------
__global__ __launch_bounds__(256) void k_prep(
    const float* __restrict__ Wih, const float* __restrict__ Whh,
    const float* __restrict__ bih, const float* __restrict__ bhh,
    const float* __restrict__ W1, const float* __restrict__ W2,
    ushort* __restrict__ Wih_hi, ushort* __restrict__ Wih_lo,
    ushort* __restrict__ Wsum_hi, ushort* __restrict__ Wsum_lo,
    ushort* __restrict__ W1hi, ushort* __restrict__ W1lo,
    ushort* __restrict__ W2hi, ushort* __restrict__ W2lo,
    float* __restrict__ bsum)
{
    int i = blockIdx.x * 256 + threadIdx.x;
    ushort h, l;
    if (i < 16384) {
        float wi = Wih[i];
        float wsv = wi + Whh[i];
        split_bf16(wi, h, l);  Wih_hi[i] = h;  Wih_lo[i] = l;
        split_bf16(wsv, h, l); Wsum_hi[i] = h; Wsum_lo[i] = l;
    }
    if (i < 12288) { split_bf16(W1[i], h, l); W1hi[i] = h; W1lo[i] = l; }
    if (i < 1024)  { split_bf16(W2[i], h, l); W2hi[i] = h; W2lo[i] = l; }
    if (i < 256)   bsum[i] = bih[i] + bhh[i];
}

// ---------------- k_red: fixed-order BN-stats reduce -> scale/shift (deterministic) ----------------
__global__ __launch_bounds__(256) void k_red(const float* __restrict__ part,
                                             const float* __restrict__ g,
                                             const float* __restrict__ be,
                                             float* __restrict__ scsh) {
    __shared__ float rs[8][32], rq[8][32];
    const int t = threadIdx.x, ch = t & 31, sl = t >> 5;
    float s = 0.f, q = 0.f;
    #pragma unroll 4
    for (int i = 0; i < 128; ++i) {
        int b = sl * 128 + i;
        s += part[b * 32 + ch];
        q += part[32768 + b * 32 + ch];
    }
    rs[sl][ch] = s; rq[sl][ch] = q;
    __syncthreads();
    if (t < 32) {
        float ss = 0.f, qq = 0.f;
        #pragma unroll
        for (int k = 0; k < 8; ++k) { ss += rs[k][t]; qq += rq[k][t]; }
        float mu = ss * (1.f / 16384.f);
        float va = qq * (1.f / 16384.f) - mu * mu;
        float sc = g[t] * rsqrtf(va + EPSV);
        scsh[t] = sc; scsh[32 + t] = be[t] - mu * sc;
    }
}

// ---------------- kernel 1: pre = [x0|x1|x2] @ W1^T + b1 (MFMA), + BN1 partial stats ----------------
__global__ __launch_bounds__(256) void k_mlp1(
    const float* __restrict__ x0, const float* __restrict__ x1, const float* __restrict__ x2,
    const ushort* __restrict__ W1hi, const ushort* __restrict__ W1lo,
    const float* __restrict__ b1,
    float* __restrict__ pre, float* __restrict__ st1p)
{
    __shared__ __align__(16) ushort xhi[32 * 392];
    __shared__ __align__(16) ushort xlo[32 * 392];
    const int tid = threadIdx.x;
    const int r0  = blockIdx.x * 32;

    for (int a = 0; a < 3; ++a) {
        const float* xp = (a == 0) ? x0 : (a == 1) ? x1 : x2;
        const float4* src = (const float4*)(xp + (size_t)r0 * 128);
        #pragma unroll
        for (int it = 0; it < 4; ++it) {
            int i = it * 256 + tid;
            int row = i >> 5, c4 = i & 31;
            float4 v = src[i];
            ushort h0, l0, h1, l1, h2, l2, h3, l3;
            split_bf16(v.x, h0, l0); split_bf16(v.y, h1, l1);
            split_bf16(v.z, h2, l2); split_bf16(v.w, h3, l3);
            int ofs = row * 392 + a * 128 + c4 * 4;
            *(ushort4*)&xhi[ofs] = make_ushort4(h0, h1, h2, h3);
            *(ushort4*)&xlo[ofs] = make_ushort4(l0, l1, l2, l3);
        }
    }
    __syncthreads();

    const int lane = tid & 63, l15 = lane & 15, lg = lane >> 4, q = tid >> 6;
    const int m0 = (q & 1) * 16, n0 = (q >> 1) * 16;
    const float bias = b1[n0 + l15];
    f32x4 acc = {bias, bias, bias, bias};
    #pragma unroll
    for (int kt = 0; kt < 12; ++kt) {
        bf16x8 ahi = *(const bf16x8*)&xhi[(m0 + l15) * 392 + kt * 32 + lg * 8];
        bf16x8 alo = *(const bf16x8*)&xlo[(m0 + l15) * 392 + kt * 32 + lg * 8];
        bf16x8 bhi = *(const bf16x8*)(W1hi + (size_t)(n0 + l15) * 384 + kt * 32 + lg * 8);
        bf16x8 blo = *(const bf16x8*)(W1lo + (size_t)(n0 + l15) * 384 + kt * 32 + lg * 8);
        acc = __builtin_amdgcn_mfma_f32_16x16x32_bf16(ahi, bhi, acc, 0, 0, 0);
        acc = __builtin_amdgcn_mfma_f32_16x16x32_bf16(ahi, blo, acc, 0, 0, 0);
        acc = __builtin_amdgcn_mfma_f32_16x16x32_bf16(alo, bhi, acc, 0, 0, 0);
    }
    #pragma unroll
    for (int rg = 0; rg < 4; ++rg)
        pre[(size_t)(r0 + m0 + lg * 4 + rg) * 32 + n0 + l15] = acc[rg];
    float s  = (acc[0] + acc[1]) + (acc[2] + acc[3]);
    float sq = (acc[0] * acc[0] + acc[1] * acc[1]) + (acc[2] * acc[2] + acc[3] * acc[3]);
    s  += __shfl_xor(s, 16);  s  += __shfl_xor(s, 32);
    sq += __shfl_xor(sq, 16); sq += __shfl_xor(sq, 32);
    if (lg == 0) {
        int slot = (blockIdx.x * 2 + (q & 1)) * 32 + n0 + l15;
        st1p[slot] = s;
        st1p[32768 + slot] = sq;
    }
}

// ---------------- kernel 2: h1 = relu(BN1(pre)); pre = h1 @ W2^T + b2 IN-PLACE; BN2 partials ----------------
__global__ __launch_bounds__(256) void k_mlp2(
    float* __restrict__ pre, const float* __restrict__ scsh1,
    const ushort* __restrict__ W2hi, const ushort* __restrict__ W2lo,
    const float* __restrict__ b2, float* __restrict__ st2p)
{
    __shared__ __align__(16) ushort hhi[32 * 40];
    __shared__ __align__(16) ushort hlo[32 * 40];
    __shared__ float bnsc[32], bnsh[32];
    const int tid = threadIdx.x;
    const int r0  = blockIdx.x * 32;

    if (tid < 32) { bnsc[tid] = scsh1[tid]; bnsh[tid] = scsh1[32 + tid]; }
    __syncthreads();
    {
        int row = tid >> 3, c4 = tid & 7;
        float4 v = ((const float4*)(pre + (size_t)r0 * 32))[tid];
        float e0 = fmaxf(fmaf(v.x, bnsc[c4 * 4 + 0], bnsh[c4 * 4 + 0]), 0.f);
        float e1 = fmaxf(fmaf(v.y, bnsc[c4 * 4 + 1], bnsh[c4 * 4 + 1]), 0.f);
        float e2 = fmaxf(fmaf(v.z, bnsc[c4 * 4 + 2], bnsh[c4 * 4 + 2]), 0.f);
        float e3 = fmaxf(fmaf(v.w, bnsc[c4 * 4 + 3], bnsh[c4 * 4 + 3]), 0.f);
        ushort h0, l0, h1, l1, h2, l2, h3, l3;
        split_bf16(e0, h0, l0); split_bf16(e1, h1, l1);
        split_bf16(e2, h2, l2); split_bf16(e3, h3, l3);
        int ofs = row * 40 + c4 * 4;
        *(ushort4*)&hhi[ofs] = make_ushort4(h0, h1, h2, h3);
        *(ushort4*)&hlo[ofs] = make_ushort4(l0, l1, l2, l3);
    }
    __syncthreads();

    const int lane = tid & 63, l15 = lane & 15, lg = lane >> 4, q = tid >> 6;
    const int m0 = (q & 1) * 16, n0 = (q >> 1) * 16;
    const float bias = b2[n0 + l15];
    f32x4 acc = {bias, bias, bias, bias};
    bf16x8 ahi = *(const bf16x8*)&hhi[(m0 + l15) * 40 + lg * 8];
    bf16x8 alo = *(const bf16x8*)&hlo[(m0 + l15) * 40 + lg * 8];
    bf16x8 bhi = *(const bf16x8*)(W2hi + (size_t)(n0 + l15) * 32 + lg * 8);
    bf16x8 blo = *(const bf16x8*)(W2lo + (size_t)(n0 + l15) * 32 + lg * 8);
    acc = __builtin_amdgcn_mfma_f32_16x16x32_bf16(ahi, bhi, acc, 0, 0, 0);
    acc = __builtin_amdgcn_mfma_f32_16x16x32_bf16(ahi, blo, acc, 0, 0, 0);
    acc = __builtin_amdgcn_mfma_f32_16x16x32_bf16(alo, bhi, acc, 0, 0, 0);

    #pragma unroll
    for (int rg = 0; rg < 4; ++rg)
        pre[(size_t)(r0 + m0 + lg * 4 + rg) * 32 + n0 + l15] = acc[rg];
    float s  = (acc[0] + acc[1]) + (acc[2] + acc[3]);
    float sq = (acc[0] * acc[0] + acc[1] * acc[1]) + (acc[2] * acc[2] + acc[3] * acc[3]);
    s  += __shfl_xor(s, 16);  s  += __shfl_xor(s, 32);
    sq += __shfl_xor(sq, 16); sq += __shfl_xor(sq, 32);
    if (lg == 0) {
        int slot = (blockIdx.x * 2 + (q & 1)) * 32 + n0 + l15;
        st2p[slot] = s;
        st2p[32768 + slot] = sq;
    }
}

// ---------------- kernel 3: BN2 -> ReLU -> m = h2@W3^T+b3 -> 26-step LSTM via MFMA ----------------
// 1024 blocks x 256 thr; block = 16 rows; 4 blocks/CU (grid-provided overlap).
// Wave q owns u-block [16q,16q+16). h via dbuf LDS (bf16 hi/lo for MFMA A, fp32 for coalesced
// out-store); weights resident in VGPRs; 1 barrier/step.
__global__ __launch_bounds__(256, 2) void k_lstm(
    const float* __restrict__ pre, const float* __restrict__ scsh2,
    const float* __restrict__ W3, const float* __restrict__ b3,
    const ushort* __restrict__ Wih_hi, const ushort* __restrict__ Wih_lo,
    const ushort* __restrict__ Wsum_hi, const ushort* __restrict__ Wsum_lo,
    const float* __restrict__ bsum, float* __restrict__ out)
{
    __shared__ __align__(16) ushort hhi[2][16][72];
    __shared__ __align__(16) ushort hlo[2][16][72];
    __shared__ __align__(16) float hf32[2][16][68];
    __shared__ float bn2sc[32], bn2sh[32];
    const int tid  = threadIdx.x;
    const int lane = tid & 63, l15 = lane & 15, lg = lane >> 4, q = tid >> 6;
    const int r0   = blockIdx.x * 16;

    if (tid < 32) { bn2sc[tid] = scsh2[tid]; bn2sh[tid] = scsh2[32 + tid]; }
    __syncthreads();

    // ---- MLP tail: m = relu(BN2(pre)) @ W3^T + b3; thread (row=tid&15, seg=tid>>4) -> 4 u
    {
        const int row = tid & 15, seg = tid >> 4;
        float h2[32];
        const float4* pr = (const float4*)(pre + (size_t)(r0 + row) * 32);
        #pragma unroll
        for (int j4 = 0; j4 < 8; ++j4) {
            float4 v = pr[j4];
            h2[j4 * 4 + 0] = v.x; h2[j4 * 4 + 1] = v.y;
            h2[j4 * 4 + 2] = v.z; h2[j4 * 4 + 3] = v.w;
        }
        #pragma unroll
        for (int j = 0; j < 32; ++j) h2[j] = fmaxf(fmaf(h2[j], bn2sc[j], bn2sh[j]), 0.f);
        #pragma unroll
        for (int uu = 0; uu < 4; ++uu) {
            int u = seg * 4 + uu;
            const float* w = W3 + u * 32;
            float a0 = 0.f, a1 = 0.f, a2 = 0.f, a3 = 0.f;
            #pragma unroll
            for (int k = 0; k < 32; k += 4) {
                a0 = fmaf(h2[k + 0], w[k + 0], a0);
                a1 = fmaf(h2[k + 1], w[k + 1], a1);
                a2 = fmaf(h2[k + 2], w[k + 2], a2);
                a3 = fmaf(h2[k + 3], w[k + 3], a3);
            }
            float m = b3[u] + ((a0 + a1) + (a2 + a3));
            ushort mh, ml; split_bf16(m, mh, ml);
            hhi[0][row][u] = mh;
            hlo[0][row][u] = ml;
        }
    }

    float bias[4];
    #pragma unroll
    for (int nt = 0; nt < 4; ++nt) bias[nt] = bsum[nt * 64 + q * 16 + l15];
    float c[4] = {0.f, 0.f, 0.f, 0.f};

    bf16x8 Bhi[4][2], Blo[4][2];
    const size_t wofs = (size_t)(q * 16 + l15) * 64 + lg * 8;
    #pragma unroll
    for (int nt = 0; nt < 4; ++nt)
        #pragma unroll
        for (int kt = 0; kt < 2; ++kt) {
            Bhi[nt][kt] = *(const bf16x8*)(Wih_hi + (size_t)nt * 4096 + wofs + kt * 32);
            Blo[nt][kt] = *(const bf16x8*)(Wih_lo + (size_t)nt * 4096 + wofs + kt * 32);
        }
    __syncthreads();

    #pragma unroll 1
    for (int s = 0; s <= 25; ++s) {
        const int buf = s & 1, nbuf = buf ^ 1;

        // ---- coalesced store of h^s (fp32, written during step s-1) -> out slot s-2
        if (s >= 2) {
            int row = tid >> 4, c4 = tid & 15;   // 256 float4 = 16 rows x 64 cols
            float4 v = *(const float4*)&hf32[buf][row][c4 * 4];
            *(float4*)&out[(size_t)(r0 + row) * 1600 + (size_t)(s - 2) * 64 + c4 * 4] = v;
        }

        f32x4 acc[4];
        #pragma unroll
        for (int nt = 0; nt < 4; ++nt)
            acc[nt] = (f32x4){bias[nt], bias[nt], bias[nt], bias[nt]};

        #pragma unroll
        for (int kt = 0; kt < 2; ++kt) {
            bf16x8 ahi = *(const bf16x8*)&hhi[buf][l15][kt * 32 + lg * 8];
            bf16x8 alo = *(const bf16x8*)&hlo[buf][l15][kt * 32 + lg * 8];
            #pragma unroll
            for (int nt = 0; nt < 4; ++nt) {
                acc[nt] = __builtin_amdgcn_mfma_f32_16x16x32_bf16(ahi, Bhi[nt][kt], acc[nt], 0, 0, 0);
                acc[nt] = __builtin_amdgcn_mfma_f32_16x16x32_bf16(ahi, Blo[nt][kt], acc[nt], 0, 0, 0);
                acc[nt] = __builtin_amdgcn_mfma_f32_16x16x32_bf16(alo, Bhi[nt][kt], acc[nt], 0, 0, 0);
            }
        }

        // ---- activations; D layout: col=l15 (-> u), row = lg*4+rg
        const int u = q * 16 + l15;
        #pragma unroll
        for (int rg = 0; rg < 4; ++rg) {
            int row = lg * 4 + rg;
            float iv = acc[0][rg], fv = acc[1][rg];
            float gv = acc[2][rg], ov = acc[3][rg];
            float cc = sigm(fv) * c[rg] + sigm(iv) * tanh_fast(gv);
            c[rg] = cc;
            float hn = sigm(ov) * tanh_fast(cc);
            ushort hh, hl; split_bf16(hn, hh, hl);
            hhi[nbuf][row][u] = hh;
            hlo[nbuf][row][u] = hl;
            hf32[nbuf][row][u] = hn;
        }

        if (s == 0) {
            #pragma unroll
            for (int nt = 0; nt < 4; ++nt)
                #pragma unroll
                for (int kt = 0; kt < 2; ++kt) {
                    Bhi[nt][kt] = *(const bf16x8*)(Wsum_hi + (size_t)nt * 4096 + wofs + kt * 32);
                    Blo[nt][kt] = *(const bf16x8*)(Wsum_lo + (size_t)nt * 4096 + wofs + kt * 32);
                }
        }
        __syncthreads();
    }

    // ---- epilogue: store h^26 -> out slot 24 (in hf32[0], written at s=25)
    {
        int row = tid >> 4, c4 = tid & 15;
        float4 v = *(const float4*)&hf32[0][row][c4 * 4];
        *(float4*)&out[(size_t)(r0 + row) * 1600 + (size_t)24 * 64 + c4 * 4] = v;
    }
}

extern "C" void kernel_launch(void* const* d_in, const int* in_sizes, int n_in,
                              void* d_out, int out_size, void* d_ws, size_t ws_size,
                              hipStream_t stream) {
    const float* x0   = (const float*)d_in[0];
    const float* x1   = (const float*)d_in[1];
    const float* x2   = (const float*)d_in[2];
    const float* W1   = (const float*)d_in[3];
    const float* b1   = (const float*)d_in[4];
    const float* g1   = (const float*)d_in[5];
    const float* be1  = (const float*)d_in[6];
    const float* W2   = (const float*)d_in[7];
    const float* b2   = (const float*)d_in[8];
    const float* g2   = (const float*)d_in[9];
    const float* be2  = (const float*)d_in[10];
    const float* W3   = (const float*)d_in[11];
    const float* b3   = (const float*)d_in[12];
    const float* Wih  = (const float*)d_in[13];
    const float* Whh  = (const float*)d_in[14];
    const float* bih  = (const float*)d_in[15];
    const float* bhh  = (const float*)d_in[16];

    float* ws    = (float*)d_ws;
    float* pre   = ws;                   // 524288 floats (pre1, then pre2 in-place)
    float* st1p  = ws + 524288;          // 65536
    float* st2p  = ws + 589824;          // 65536
    float* scsh1 = ws + 655360;          // 64
    float* scsh2 = ws + 655424;          // 64
    float* bsum  = ws + 655488;          // 256
    ushort* ub   = (ushort*)(ws + 655744);
    ushort* Wih_hi  = ub;                // 16384
    ushort* Wih_lo  = ub + 16384;
    ushort* Wsum_hi = ub + 32768;
    ushort* Wsum_lo = ub + 49152;
    ushort* W1hi    = ub + 65536;        // 12288
    ushort* W1lo    = ub + 77824;
    ushort* W2hi    = ub + 90112;        // 1024
    ushort* W2lo    = ub + 91136;        // end 92160

    hipLaunchKernelGGL(k_prep, dim3(64), dim3(256), 0, stream,
                       Wih, Whh, bih, bhh, W1, W2,
                       Wih_hi, Wih_lo, Wsum_hi, Wsum_lo, W1hi, W1lo, W2hi, W2lo, bsum);
    hipLaunchKernelGGL(k_mlp1, dim3(512), dim3(256), 0, stream,
                       x0, x1, x2, W1hi, W1lo, b1, pre, st1p);
    hipLaunchKernelGGL(k_red, dim3(1), dim3(256), 0, stream, st1p, g1, be1, scsh1);
    hipLaunchKernelGGL(k_mlp2, dim3(512), dim3(256), 0, stream,
                       pre, scsh1, W2hi, W2lo, b2, st2p);
    hipLaunchKernelGGL(k_red, dim3(1), dim3(256), 0, stream, st2p, g2, be2, scsh2);
    hipLaunchKernelGGL(k_lstm, dim3(1024), dim3(256), 0, stream,
                       pre, scsh2, W3, b3,
                       Wih_hi, Wih_lo, Wsum_hi, Wsum_lo, bsum, (float*)d_out);
}

// Round 7
// 100.917 us; speedup vs baseline: 2.6933x; 1.0856x over previous
//
#include <hip/hip_runtime.h>

// Predictor: MLP3 (Linear+BN(train)+ReLU x2, Linear) -> LSTM(64), 1 cond + 25 self-feed steps.
// B=16384, OUT=128 (x3 -> 384), HID=32, LSTM_H=64, NPRED=25. Output (B,25,64) fp32.
// All GEMMs via split-precision bf16 MFMA: P = A_hi*B_hi + A_hi*B_lo + A_lo*B_hi (fp32 accum).
// BN stats BIT-DETERMINISTIC (slot partials + fixed-order reduce; float atomics diverge replays).
// k_lstm: ping-pong dual 16-row groups per 32-row block; each barrier interval = MFMA(one group)
// || activation(other group) so MFMA and trans/VALU pipes are co-fed from one wave's stream.
// Gate weights pre-scaled by log2e (2log2e for g-gate) -> exp2-domain activations, 8 trans/cell.
// NOTE: never use __launch_bounds__ min-waves >= 4 here -- caps VGPR at 64, spills resident
// weights (R4/R5: FETCH 470MB, 3x slowdown). (256,2) is safe.

#define EPSV 1e-5f
#define LOG2E 1.4426950408889634f
#define K2    2.8853900817779268f   // 2*log2e

typedef __attribute__((ext_vector_type(8))) short bf16x8;
typedef __attribute__((ext_vector_type(4))) float f32x4;

__device__ __forceinline__ float rcp_f(float x) { return __builtin_amdgcn_rcpf(x); }
__device__ __forceinline__ void split_bf16(float x, ushort& hi, ushort& lo) {
    unsigned xb = __builtin_bit_cast(unsigned, x);
    hi = (ushort)(xb >> 16);
    float hif = __builtin_bit_cast(float, xb & 0xffff0000u);
    unsigned lb = __builtin_bit_cast(unsigned, x - hif);
    lo = (ushort)(lb >> 16);
}

// ---------------- kernel 0: split weights to bf16 hi/lo; LSTM gate rows pre-scaled ----------------
__global__ __launch_bounds__(256) void k_prep(
    const float* __restrict__ Wih, const float* __restrict__ Whh,
    const float* __restrict__ bih, const float* __restrict__ bhh,
    const float* __restrict__ W1, const float* __restrict__ W2,
    ushort* __restrict__ Wih_hi, ushort* __restrict__ Wih_lo,
    ushort* __restrict__ Wsum_hi, ushort* __restrict__ Wsum_lo,
    ushort* __restrict__ W1hi, ushort* __restrict__ W1lo,
    ushort* __restrict__ W2hi, ushort* __restrict__ W2lo,
    float* __restrict__ bsum)
{
    int i = blockIdx.x * 256 + threadIdx.x;
    ushort h, l;
    if (i < 16384) {
        int j = i >> 6;                                   // gate row 0..255 (i,f,g,o x64)
        float sc = (j >= 128 && j < 192) ? K2 : LOG2E;    // g-gate: 2*log2e (tanh), else log2e
        float wi  = Wih[i] * sc;
        float wsv = (Wih[i] + Whh[i]) * sc;
        split_bf16(wi, h, l);  Wih_hi[i] = h;  Wih_lo[i] = l;
        split_bf16(wsv, h, l); Wsum_hi[i] = h; Wsum_lo[i] = l;
    }
    if (i < 12288) { split_bf16(W1[i], h, l); W1hi[i] = h; W1lo[i] = l; }
    if (i < 1024)  { split_bf16(W2[i], h, l); W2hi[i] = h; W2lo[i] = l; }
    if (i < 256) {
        float sc = (i >= 128 && i < 192) ? K2 : LOG2E;
        bsum[i] = (bih[i] + bhh[i]) * sc;
    }
}

// ---------------- k_red: fixed-order BN-stats reduce -> scale/shift (deterministic) ----------------
__global__ __launch_bounds__(256) void k_red(const float* __restrict__ part,
                                             const float* __restrict__ g,
                                             const float* __restrict__ be,
                                             float* __restrict__ scsh) {
    __shared__ float rs[8][32], rq[8][32];
    const int t = threadIdx.x, ch = t & 31, sl = t >> 5;
    float s = 0.f, q = 0.f;
    #pragma unroll 4
    for (int i = 0; i < 128; ++i) {
        int b = sl * 128 + i;
        s += part[b * 32 + ch];
        q += part[32768 + b * 32 + ch];
    }
    rs[sl][ch] = s; rq[sl][ch] = q;
    __syncthreads();
    if (t < 32) {
        float ss = 0.f, qq = 0.f;
        #pragma unroll
        for (int k = 0; k < 8; ++k) { ss += rs[k][t]; qq += rq[k][t]; }
        float mu = ss * (1.f / 16384.f);
        float va = qq * (1.f / 16384.f) - mu * mu;
        float sc = g[t] * rsqrtf(va + EPSV);
        scsh[t] = sc; scsh[32 + t] = be[t] - mu * sc;
    }
}

// ---------------- kernel 1: pre = [x0|x1|x2] @ W1^T + b1 (MFMA), + BN1 partial stats ----------------
__global__ __launch_bounds__(256) void k_mlp1(
    const float* __restrict__ x0, const float* __restrict__ x1, const float* __restrict__ x2,
    const ushort* __restrict__ W1hi, const ushort* __restrict__ W1lo,
    const float* __restrict__ b1,
    float* __restrict__ pre, float* __restrict__ st1p)
{
    __shared__ __align__(16) ushort xhi[32 * 392];
    __shared__ __align__(16) ushort xlo[32 * 392];
    const int tid = threadIdx.x;
    const int r0  = blockIdx.x * 32;

    for (int a = 0; a < 3; ++a) {
        const float* xp = (a == 0) ? x0 : (a == 1) ? x1 : x2;
        const float4* src = (const float4*)(xp + (size_t)r0 * 128);
        #pragma unroll
        for (int it = 0; it < 4; ++it) {
            int i = it * 256 + tid;
            int row = i >> 5, c4 = i & 31;
            float4 v = src[i];
            ushort h0, l0, h1, l1, h2, l2, h3, l3;
            split_bf16(v.x, h0, l0); split_bf16(v.y, h1, l1);
            split_bf16(v.z, h2, l2); split_bf16(v.w, h3, l3);
            int ofs = row * 392 + a * 128 + c4 * 4;
            *(ushort4*)&xhi[ofs] = make_ushort4(h0, h1, h2, h3);
            *(ushort4*)&xlo[ofs] = make_ushort4(l0, l1, l2, l3);
        }
    }
    __syncthreads();

    const int lane = tid & 63, l15 = lane & 15, lg = lane >> 4, q = tid >> 6;
    const int m0 = (q & 1) * 16, n0 = (q >> 1) * 16;
    const float bias = b1[n0 + l15];
    f32x4 acc = {bias, bias, bias, bias};
    #pragma unroll
    for (int kt = 0; kt < 12; ++kt) {
        bf16x8 ahi = *(const bf16x8*)&xhi[(m0 + l15) * 392 + kt * 32 + lg * 8];
        bf16x8 alo = *(const bf16x8*)&xlo[(m0 + l15) * 392 + kt * 32 + lg * 8];
        bf16x8 bhi = *(const bf16x8*)(W1hi + (size_t)(n0 + l15) * 384 + kt * 32 + lg * 8);
        bf16x8 blo = *(const bf16x8*)(W1lo + (size_t)(n0 + l15) * 384 + kt * 32 + lg * 8);
        acc = __builtin_amdgcn_mfma_f32_16x16x32_bf16(ahi, bhi, acc, 0, 0, 0);
        acc = __builtin_amdgcn_mfma_f32_16x16x32_bf16(ahi, blo, acc, 0, 0, 0);
        acc = __builtin_amdgcn_mfma_f32_16x16x32_bf16(alo, bhi, acc, 0, 0, 0);
    }
    #pragma unroll
    for (int rg = 0; rg < 4; ++rg)
        pre[(size_t)(r0 + m0 + lg * 4 + rg) * 32 + n0 + l15] = acc[rg];
    float s  = (acc[0] + acc[1]) + (acc[2] + acc[3]);
    float sq = (acc[0] * acc[0] + acc[1] * acc[1]) + (acc[2] * acc[2] + acc[3] * acc[3]);
    s  += __shfl_xor(s, 16);  s  += __shfl_xor(s, 32);
    sq += __shfl_xor(sq, 16); sq += __shfl_xor(sq, 32);
    if (lg == 0) {
        int slot = (blockIdx.x * 2 + (q & 1)) * 32 + n0 + l15;
        st1p[slot] = s;
        st1p[32768 + slot] = sq;
    }
}

// ---------------- kernel 2: h1 = relu(BN1(pre)); pre = h1 @ W2^T + b2 IN-PLACE; BN2 partials ----------------
__global__ __launch_bounds__(256) void k_mlp2(
    float* __restrict__ pre, const float* __restrict__ scsh1,
    const ushort* __restrict__ W2hi, const ushort* __restrict__ W2lo,
    const float* __restrict__ b2, float* __restrict__ st2p)
{
    __shared__ __align__(16) ushort hhi[32 * 40];
    __shared__ __align__(16) ushort hlo[32 * 40];
    __shared__ float bnsc[32], bnsh[32];
    const int tid = threadIdx.x;
    const int r0  = blockIdx.x * 32;

    if (tid < 32) { bnsc[tid] = scsh1[tid]; bnsh[tid] = scsh1[32 + tid]; }
    __syncthreads();
    {
        int row = tid >> 3, c4 = tid & 7;
        float4 v = ((const float4*)(pre + (size_t)r0 * 32))[tid];
        float e0 = fmaxf(fmaf(v.x, bnsc[c4 * 4 + 0], bnsh[c4 * 4 + 0]), 0.f);
        float e1 = fmaxf(fmaf(v.y, bnsc[c4 * 4 + 1], bnsh[c4 * 4 + 1]), 0.f);
        float e2 = fmaxf(fmaf(v.z, bnsc[c4 * 4 + 2], bnsh[c4 * 4 + 2]), 0.f);
        float e3 = fmaxf(fmaf(v.w, bnsc[c4 * 4 + 3], bnsh[c4 * 4 + 3]), 0.f);
        ushort h0, l0, h1, l1, h2, l2, h3, l3;
        split_bf16(e0, h0, l0); split_bf16(e1, h1, l1);
        split_bf16(e2, h2, l2); split_bf16(e3, h3, l3);
        int ofs = row * 40 + c4 * 4;
        *(ushort4*)&hhi[ofs] = make_ushort4(h0, h1, h2, h3);
        *(ushort4*)&hlo[ofs] = make_ushort4(l0, l1, l2, l3);
    }
    __syncthreads();

    const int lane = tid & 63, l15 = lane & 15, lg = lane >> 4, q = tid >> 6;
    const int m0 = (q & 1) * 16, n0 = (q >> 1) * 16;
    const float bias = b2[n0 + l15];
    f32x4 acc = {bias, bias, bias, bias};
    bf16x8 ahi = *(const bf16x8*)&hhi[(m0 + l15) * 40 + lg * 8];
    bf16x8 alo = *(const bf16x8*)&hlo[(m0 + l15) * 40 + lg * 8];
    bf16x8 bhi = *(const bf16x8*)(W2hi + (size_t)(n0 + l15) * 32 + lg * 8);
    bf16x8 blo = *(const bf16x8*)(W2lo + (size_t)(n0 + l15) * 32 + lg * 8);
    acc = __builtin_amdgcn_mfma_f32_16x16x32_bf16(ahi, bhi, acc, 0, 0, 0);
    acc = __builtin_amdgcn_mfma_f32_16x16x32_bf16(ahi, blo, acc, 0, 0, 0);
    acc = __builtin_amdgcn_mfma_f32_16x16x32_bf16(alo, bhi, acc, 0, 0, 0);

    #pragma unroll
    for (int rg = 0; rg < 4; ++rg)
        pre[(size_t)(r0 + m0 + lg * 4 + rg) * 32 + n0 + l15] = acc[rg];
    float s  = (acc[0] + acc[1]) + (acc[2] + acc[3]);
    float sq = (acc[0] * acc[0] + acc[1] * acc[1]) + (acc[2] * acc[2] + acc[3] * acc[3]);
    s  += __shfl_xor(s, 16);  s  += __shfl_xor(s, 32);
    sq += __shfl_xor(sq, 16); sq += __shfl_xor(sq, 32);
    if (lg == 0) {
        int slot = (blockIdx.x * 2 + (q & 1)) * 32 + n0 + l15;
        st2p[slot] = s;
        st2p[32768 + slot] = sq;
    }
}

// ---------------- kernel 3: BN2 -> ReLU -> m -> 26-step LSTM, ping-pong dual groups ----------------
// 512 blocks x 256 thr; block = 32 rows = groups A(0..15), B(16..31); wave q owns u-quadrant.
// Interval = { MFMA(one group) || activation(other group) }; 2 barriers/step for 2 groups.
__global__ __launch_bounds__(256, 2) void k_lstm(
    const float* __restrict__ pre, const float* __restrict__ scsh2,
    const float* __restrict__ W3, const float* __restrict__ b3,
    const ushort* __restrict__ Wih_hi, const ushort* __restrict__ Wih_lo,
    const ushort* __restrict__ Wsum_hi, const ushort* __restrict__ Wsum_lo,
    const float* __restrict__ bsum, float* __restrict__ out)
{
    __shared__ __align__(16) ushort hhi[2][2][16][72];  // [group][buf][row][u]
    __shared__ __align__(16) ushort hlo[2][2][16][72];
    __shared__ float bn2sc[32], bn2sh[32];
    const int tid  = threadIdx.x;
    const int lane = tid & 63, l15 = lane & 15, lg = lane >> 4, q = tid >> 6;
    const int r0   = blockIdx.x * 32;

    if (tid < 32) { bn2sc[tid] = scsh2[tid]; bn2sh[tid] = scsh2[32 + tid]; }
    __syncthreads();

    // ---- MLP tail: m = relu(BN2(pre)) @ W3^T + b3 for 32 rows; write into buf 0 of each group
    {
        const int row = tid & 31, seg = tid >> 5;
        float h2[32];
        const float4* pr = (const float4*)(pre + (size_t)(r0 + row) * 32);
        #pragma unroll
        for (int j4 = 0; j4 < 8; ++j4) {
            float4 v = pr[j4];
            h2[j4 * 4 + 0] = v.x; h2[j4 * 4 + 1] = v.y;
            h2[j4 * 4 + 2] = v.z; h2[j4 * 4 + 3] = v.w;
        }
        #pragma unroll
        for (int j = 0; j < 32; ++j) h2[j] = fmaxf(fmaf(h2[j], bn2sc[j], bn2sh[j]), 0.f);
        #pragma unroll
        for (int uu = 0; uu < 8; ++uu) {
            int u = seg * 8 + uu;
            const float* w = W3 + u * 32;
            float a0 = 0.f, a1 = 0.f, a2 = 0.f, a3 = 0.f;
            #pragma unroll
            for (int k = 0; k < 32; k += 4) {
                a0 = fmaf(h2[k + 0], w[k + 0], a0);
                a1 = fmaf(h2[k + 1], w[k + 1], a1);
                a2 = fmaf(h2[k + 2], w[k + 2], a2);
                a3 = fmaf(h2[k + 3], w[k + 3], a3);
            }
            float m = b3[u] + ((a0 + a1) + (a2 + a3));
            ushort mh, ml; split_bf16(m, mh, ml);
            hhi[row >> 4][0][row & 15][u] = mh;
            hlo[row >> 4][0][row & 15][u] = ml;
        }
    }

    float bias[4];
    #pragma unroll
    for (int nt = 0; nt < 4; ++nt) bias[nt] = bsum[nt * 64 + q * 16 + l15];
    float cA[4] = {0.f, 0.f, 0.f, 0.f}, cB[4] = {0.f, 0.f, 0.f, 0.f};

    bf16x8 Bhi[4][2], Blo[4][2];
    const size_t wofs = (size_t)(q * 16 + l15) * 64 + lg * 8;
    #pragma unroll
    for (int nt = 0; nt < 4; ++nt)
        #pragma unroll
        for (int kt = 0; kt < 2; ++kt) {
            Bhi[nt][kt] = *(const bf16x8*)(Wih_hi + (size_t)nt * 4096 + wofs + kt * 32);
            Blo[nt][kt] = *(const bf16x8*)(Wih_lo + (size_t)nt * 4096 + wofs + kt * 32);
        }
    __syncthreads();

#define MFMA_GATES(ACC, G, BUF)                                                  \
    {                                                                            \
        _Pragma("unroll")                                                        \
        for (int nt = 0; nt < 4; ++nt)                                           \
            ACC[nt] = (f32x4){bias[nt], bias[nt], bias[nt], bias[nt]};           \
        _Pragma("unroll")                                                        \
        for (int kt = 0; kt < 2; ++kt) {                                         \
            bf16x8 ahi = *(const bf16x8*)&hhi[G][BUF][l15][kt * 32 + lg * 8];    \
            bf16x8 alo = *(const bf16x8*)&hlo[G][BUF][l15][kt * 32 + lg * 8];    \
            _Pragma("unroll")                                                    \
            for (int nt = 0; nt < 4; ++nt) {                                     \
                ACC[nt] = __builtin_amdgcn_mfma_f32_16x16x32_bf16(ahi, Bhi[nt][kt], ACC[nt], 0, 0, 0); \
                ACC[nt] = __builtin_amdgcn_mfma_f32_16x16x32_bf16(ahi, Blo[nt][kt], ACC[nt], 0, 0, 0); \
                ACC[nt] = __builtin_amdgcn_mfma_f32_16x16x32_bf16(alo, Bhi[nt][kt], ACC[nt], 0, 0, 0); \
            }                                                                    \
        }                                                                        \
    }

    // exp2-domain activations: i,f,o scaled by log2e; g by 2log2e (baked into W/bsum).
    // sigm(f) = rcp(1+exp2(-f^)); sigm(i)*tanh(g) = (Bg-1)*rcp((1+Ai)(Bg+1));
    // sigm(o)*tanh(cc) = (C2-1)*rcp((1+Ao)(C2+1)), C2 = exp2(K2*cc).
#define ACT(ACC, C, G, WBUF, SLOT, WRLDS)                                        \
    {                                                                            \
        const int u = q * 16 + l15;                                              \
        _Pragma("unroll")                                                        \
        for (int rg = 0; rg < 4; ++rg) {                                         \
            int row = lg * 4 + rg;                                               \
            float iv = ACC[0][rg], fv = ACC[1][rg];                              \
            float gv = ACC[2][rg], ov = ACC[3][rg];                              \
            float Af = __builtin_amdgcn_exp2f(-fv);                              \
            float Ai = __builtin_amdgcn_exp2f(-iv);                              \
            float Bg = __builtin_amdgcn_exp2f(gv);                               \
            float sig = (Bg - 1.f) * rcp_f((1.f + Ai) * (Bg + 1.f));             \
            float cc = C[rg] * rcp_f(1.f + Af) + sig;                            \
            C[rg] = cc;                                                          \
            float Ao = __builtin_amdgcn_exp2f(-ov);                              \
            float C2 = __builtin_amdgcn_exp2f(cc * K2);                          \
            float hn = (C2 - 1.f) * rcp_f((1.f + Ao) * (C2 + 1.f));              \
            if (WRLDS) {                                                         \
                ushort hh, hl; split_bf16(hn, hh, hl);                           \
                hhi[G][WBUF][row][u] = hh;                                       \
                hlo[G][WBUF][row][u] = hl;                                       \
            }                                                                    \
            if ((SLOT) >= 0)                                                     \
                out[(size_t)(r0 + (G)*16 + row) * 1600 + (size_t)(SLOT) * 64 + u] = hn; \
        }                                                                        \
    }

    f32x4 accA[4], accB[4];

    // ---- prologue: step 0 (input m, weights Wih)
    MFMA_GATES(accA, 0, 0);
    MFMA_GATES(accB, 1, 0);
    // switch resident weights to Wsum for self-feed steps (loads overlap act below)
    #pragma unroll
    for (int nt = 0; nt < 4; ++nt)
        #pragma unroll
        for (int kt = 0; kt < 2; ++kt) {
            Bhi[nt][kt] = *(const bf16x8*)(Wsum_hi + (size_t)nt * 4096 + wofs + kt * 32);
            Blo[nt][kt] = *(const bf16x8*)(Wsum_lo + (size_t)nt * 4096 + wofs + kt * 32);
        }
    ACT(accA, cA, 0, 1, -1, 1);     // h_A^1 -> bufA[1], no output
    __syncthreads();

    // ---- steady ping-pong: 2 intervals per step
    #pragma unroll 1
    for (int s = 1; s <= 25; ++s) {
        const int rb = s & 1, wb = rb ^ 1;
        MFMA_GATES(accA, 0, rb);          // gates_A(s) from h_A^s
        ACT(accB, cB, 1, rb, s - 2, 1);   // h_B^s -> bufB[rb], out slot s-2
        __syncthreads();
        MFMA_GATES(accB, 1, rb);          // gates_B(s) from h_B^s
        ACT(accA, cA, 0, wb, s - 1, 1);   // h_A^{s+1} -> bufA[wb], out slot s-1
        __syncthreads();
    }
    // ---- epilogue: finish group B step 25
    ACT(accB, cB, 1, 0, 24, 0);

#undef MFMA_GATES
#undef ACT
}

extern "C" void kernel_launch(void* const* d_in, const int* in_sizes, int n_in,
                              void* d_out, int out_size, void* d_ws, size_t ws_size,
                              hipStream_t stream) {
    const float* x0   = (const float*)d_in[0];
    const float* x1   = (const float*)d_in[1];
    const float* x2   = (const float*)d_in[2];
    const float* W1   = (const float*)d_in[3];
    const float* b1   = (const float*)d_in[4];
    const float* g1   = (const float*)d_in[5];
    const float* be1  = (const float*)d_in[6];
    const float* W2   = (const float*)d_in[7];
    const float* b2   = (const float*)d_in[8];
    const float* g2   = (const float*)d_in[9];
    const float* be2  = (const float*)d_in[10];
    const float* W3   = (const float*)d_in[11];
    const float* b3   = (const float*)d_in[12];
    const float* Wih  = (const float*)d_in[13];
    const float* Whh  = (const float*)d_in[14];
    const float* bih  = (const float*)d_in[15];
    const float* bhh  = (const float*)d_in[16];

    float* ws    = (float*)d_ws;
    float* pre   = ws;                   // 524288 floats (pre1, then pre2 in-place)
    float* st1p  = ws + 524288;          // 65536
    float* st2p  = ws + 589824;          // 65536
    float* scsh1 = ws + 655360;          // 64
    float* scsh2 = ws + 655424;          // 64
    float* bsum  = ws + 655488;          // 256
    ushort* ub   = (ushort*)(ws + 655744);
    ushort* Wih_hi  = ub;                // 16384
    ushort* Wih_lo  = ub + 16384;
    ushort* Wsum_hi = ub + 32768;
    ushort* Wsum_lo = ub + 49152;
    ushort* W1hi    = ub + 65536;        // 12288
    ushort* W1lo    = ub + 77824;
    ushort* W2hi    = ub + 90112;        // 1024
    ushort* W2lo    = ub + 91136;        // end 92160

    hipLaunchKernelGGL(k_prep, dim3(64), dim3(256), 0, stream,
                       Wih, Whh, bih, bhh, W1, W2,
                       Wih_hi, Wih_lo, Wsum_hi, Wsum_lo, W1hi, W1lo, W2hi, W2lo, bsum);
    hipLaunchKernelGGL(k_mlp1, dim3(512), dim3(256), 0, stream,
                       x0, x1, x2, W1hi, W1lo, b1, pre, st1p);
    hipLaunchKernelGGL(k_red, dim3(1), dim3(256), 0, stream, st1p, g1, be1, scsh1);
    hipLaunchKernelGGL(k_mlp2, dim3(512), dim3(256), 0, stream,
                       pre, scsh1, W2hi, W2lo, b2, st2p);
    hipLaunchKernelGGL(k_red, dim3(1), dim3(256), 0, stream, st2p, g2, be2, scsh2);
    hipLaunchKernelGGL(k_lstm, dim3(512), dim3(256), 0, stream,
                       pre, scsh2, W3, b3,
                       Wih_hi, Wih_lo, Wsum_hi, Wsum_lo, bsum, (float*)d_out);
}

// Round 8
// 87.809 us; speedup vs baseline: 3.0954x; 1.1493x over previous
//
#include <hip/hip_runtime.h>

// Predictor: MLP3 (Linear+BN(train)+ReLU x2, Linear) -> LSTM(64), 1 cond + 25 self-feed steps.
// B=16384, OUT=128 (x3 -> 384), HID=32, LSTM_H=64, NPRED=25. Output (B,25,64) fp32.
// All GEMMs via split-precision bf16 MFMA: P = A_hi*B_hi + A_hi*B_lo + A_lo*B_hi (fp32 accum).
// BN stats BIT-DETERMINISTIC (slot partials + fixed-order reduce; float atomics diverge replays).
// k_lstm: ping-pong dual 16-row groups per 32-row block; each barrier interval = MFMA(one group)
// || activation(other group). Gate weights pre-scaled by log2e (2log2e for g) -> exp2 domain.
// k_red: 32 blocks (one per channel) -- single-block version was ~6.5us (one CU reading 256KB).
// NOTE: never use __launch_bounds__ min-waves >= 4 here -- caps VGPR at 64, spills resident
// weights (R4/R5: FETCH 470MB, 3x slowdown). (256,2) is safe.

#define EPSV 1e-5f
#define LOG2E 1.4426950408889634f
#define K2    2.8853900817779268f   // 2*log2e

typedef __attribute__((ext_vector_type(8))) short bf16x8;
typedef __attribute__((ext_vector_type(4))) float f32x4;

__device__ __forceinline__ float rcp_f(float x) { return __builtin_amdgcn_rcpf(x); }
__device__ __forceinline__ void split_bf16(float x, ushort& hi, ushort& lo) {
    unsigned xb = __builtin_bit_cast(unsigned, x);
    hi = (ushort)(xb >> 16);
    float hif = __builtin_bit_cast(float, xb & 0xffff0000u);
    unsigned lb = __builtin_bit_cast(unsigned, x - hif);
    lo = (ushort)(lb >> 16);
}

// ---------------- kernel 0: split weights to bf16 hi/lo; LSTM gate rows pre-scaled ----------------
__global__ __launch_bounds__(256) void k_prep(
    const float* __restrict__ Wih, const float* __restrict__ Whh,
    const float* __restrict__ bih, const float* __restrict__ bhh,
    const float* __restrict__ W1, const float* __restrict__ W2,
    ushort* __restrict__ Wih_hi, ushort* __restrict__ Wih_lo,
    ushort* __restrict__ Wsum_hi, ushort* __restrict__ Wsum_lo,
    ushort* __restrict__ W1hi, ushort* __restrict__ W1lo,
    ushort* __restrict__ W2hi, ushort* __restrict__ W2lo,
    float* __restrict__ bsum)
{
    int i = blockIdx.x * 256 + threadIdx.x;
    ushort h, l;
    if (i < 16384) {
        int j = i >> 6;                                   // gate row 0..255 (i,f,g,o x64)
        float sc = (j >= 128 && j < 192) ? K2 : LOG2E;    // g-gate: 2*log2e (tanh), else log2e
        float wi  = Wih[i] * sc;
        float wsv = (Wih[i] + Whh[i]) * sc;
        split_bf16(wi, h, l);  Wih_hi[i] = h;  Wih_lo[i] = l;
        split_bf16(wsv, h, l); Wsum_hi[i] = h; Wsum_lo[i] = l;
    }
    if (i < 12288) { split_bf16(W1[i], h, l); W1hi[i] = h; W1lo[i] = l; }
    if (i < 1024)  { split_bf16(W2[i], h, l); W2hi[i] = h; W2lo[i] = l; }
    if (i < 256) {
        float sc = (i >= 128 && i < 192) ? K2 : LOG2E;
        bsum[i] = (bih[i] + bhh[i]) * sc;
    }
}

// ---------------- k_red: per-channel fixed-order BN-stats reduce (deterministic) ----------------
// 32 blocks (one per channel) x 256 thr. part: [1024][32] sums, +32768: [1024][32] sumsqs.
__global__ __launch_bounds__(256) void k_red(const float* __restrict__ part,
                                             const float* __restrict__ g,
                                             const float* __restrict__ be,
                                             float* __restrict__ scsh) {
    __shared__ float rs[256], rq[256];
    const int ch = blockIdx.x, t = threadIdx.x;
    float s = (part[t * 32 + ch] + part[(t + 256) * 32 + ch]) +
              (part[(t + 512) * 32 + ch] + part[(t + 768) * 32 + ch]);
    float q = (part[32768 + t * 32 + ch] + part[32768 + (t + 256) * 32 + ch]) +
              (part[32768 + (t + 512) * 32 + ch] + part[32768 + (t + 768) * 32 + ch]);
    rs[t] = s; rq[t] = q;
    __syncthreads();
    #pragma unroll
    for (int off = 128; off > 0; off >>= 1) {
        if (t < off) { rs[t] += rs[t + off]; rq[t] += rq[t + off]; }
        __syncthreads();
    }
    if (t == 0) {
        float mu = rs[0] * (1.f / 16384.f);
        float va = rq[0] * (1.f / 16384.f) - mu * mu;
        float sc = g[ch] * rsqrtf(va + EPSV);
        scsh[ch] = sc; scsh[32 + ch] = be[ch] - mu * sc;
    }
}

// ---------------- kernel 1: pre = [x0|x1|x2] @ W1^T + b1 (MFMA), + BN1 partial stats ----------------
__global__ __launch_bounds__(256) void k_mlp1(
    const float* __restrict__ x0, const float* __restrict__ x1, const float* __restrict__ x2,
    const ushort* __restrict__ W1hi, const ushort* __restrict__ W1lo,
    const float* __restrict__ b1,
    float* __restrict__ pre, float* __restrict__ st1p)
{
    __shared__ __align__(16) ushort xhi[32 * 392];
    __shared__ __align__(16) ushort xlo[32 * 392];
    const int tid = threadIdx.x;
    const int r0  = blockIdx.x * 32;

    for (int a = 0; a < 3; ++a) {
        const float* xp = (a == 0) ? x0 : (a == 1) ? x1 : x2;
        const float4* src = (const float4*)(xp + (size_t)r0 * 128);
        #pragma unroll
        for (int it = 0; it < 4; ++it) {
            int i = it * 256 + tid;
            int row = i >> 5, c4 = i & 31;
            float4 v = src[i];
            ushort h0, l0, h1, l1, h2, l2, h3, l3;
            split_bf16(v.x, h0, l0); split_bf16(v.y, h1, l1);
            split_bf16(v.z, h2, l2); split_bf16(v.w, h3, l3);
            int ofs = row * 392 + a * 128 + c4 * 4;
            *(ushort4*)&xhi[ofs] = make_ushort4(h0, h1, h2, h3);
            *(ushort4*)&xlo[ofs] = make_ushort4(l0, l1, l2, l3);
        }
    }
    __syncthreads();

    const int lane = tid & 63, l15 = lane & 15, lg = lane >> 4, q = tid >> 6;
    const int m0 = (q & 1) * 16, n0 = (q >> 1) * 16;
    const float bias = b1[n0 + l15];
    f32x4 acc = {bias, bias, bias, bias};
    #pragma unroll
    for (int kt = 0; kt < 12; ++kt) {
        bf16x8 ahi = *(const bf16x8*)&xhi[(m0 + l15) * 392 + kt * 32 + lg * 8];
        bf16x8 alo = *(const bf16x8*)&xlo[(m0 + l15) * 392 + kt * 32 + lg * 8];
        bf16x8 bhi = *(const bf16x8*)(W1hi + (size_t)(n0 + l15) * 384 + kt * 32 + lg * 8);
        bf16x8 blo = *(const bf16x8*)(W1lo + (size_t)(n0 + l15) * 384 + kt * 32 + lg * 8);
        acc = __builtin_amdgcn_mfma_f32_16x16x32_bf16(ahi, bhi, acc, 0, 0, 0);
        acc = __builtin_amdgcn_mfma_f32_16x16x32_bf16(ahi, blo, acc, 0, 0, 0);
        acc = __builtin_amdgcn_mfma_f32_16x16x32_bf16(alo, bhi, acc, 0, 0, 0);
    }
    #pragma unroll
    for (int rg = 0; rg < 4; ++rg)
        pre[(size_t)(r0 + m0 + lg * 4 + rg) * 32 + n0 + l15] = acc[rg];
    float s  = (acc[0] + acc[1]) + (acc[2] + acc[3]);
    float sq = (acc[0] * acc[0] + acc[1] * acc[1]) + (acc[2] * acc[2] + acc[3] * acc[3]);
    s  += __shfl_xor(s, 16);  s  += __shfl_xor(s, 32);
    sq += __shfl_xor(sq, 16); sq += __shfl_xor(sq, 32);
    if (lg == 0) {
        int slot = (blockIdx.x * 2 + (q & 1)) * 32 + n0 + l15;
        st1p[slot] = s;
        st1p[32768 + slot] = sq;
    }
}

// ---------------- kernel 2: h1 = relu(BN1(pre)); pre = h1 @ W2^T + b2 IN-PLACE; BN2 partials ----------------
__global__ __launch_bounds__(256) void k_mlp2(
    float* __restrict__ pre, const float* __restrict__ scsh1,
    const ushort* __restrict__ W2hi, const ushort* __restrict__ W2lo,
    const float* __restrict__ b2, float* __restrict__ st2p)
{
    __shared__ __align__(16) ushort hhi[32 * 40];
    __shared__ __align__(16) ushort hlo[32 * 40];
    __shared__ float bnsc[32], bnsh[32];
    const int tid = threadIdx.x;
    const int r0  = blockIdx.x * 32;

    if (tid < 32) { bnsc[tid] = scsh1[tid]; bnsh[tid] = scsh1[32 + tid]; }
    __syncthreads();
    {
        int row = tid >> 3, c4 = tid & 7;
        float4 v = ((const float4*)(pre + (size_t)r0 * 32))[tid];
        float e0 = fmaxf(fmaf(v.x, bnsc[c4 * 4 + 0], bnsh[c4 * 4 + 0]), 0.f);
        float e1 = fmaxf(fmaf(v.y, bnsc[c4 * 4 + 1], bnsh[c4 * 4 + 1]), 0.f);
        float e2 = fmaxf(fmaf(v.z, bnsc[c4 * 4 + 2], bnsh[c4 * 4 + 2]), 0.f);
        float e3 = fmaxf(fmaf(v.w, bnsc[c4 * 4 + 3], bnsh[c4 * 4 + 3]), 0.f);
        ushort h0, l0, h1, l1, h2, l2, h3, l3;
        split_bf16(e0, h0, l0); split_bf16(e1, h1, l1);
        split_bf16(e2, h2, l2); split_bf16(e3, h3, l3);
        int ofs = row * 40 + c4 * 4;
        *(ushort4*)&hhi[ofs] = make_ushort4(h0, h1, h2, h3);
        *(ushort4*)&hlo[ofs] = make_ushort4(l0, l1, l2, l3);
    }
    __syncthreads();

    const int lane = tid & 63, l15 = lane & 15, lg = lane >> 4, q = tid >> 6;
    const int m0 = (q & 1) * 16, n0 = (q >> 1) * 16;
    const float bias = b2[n0 + l15];
    f32x4 acc = {bias, bias, bias, bias};
    bf16x8 ahi = *(const bf16x8*)&hhi[(m0 + l15) * 40 + lg * 8];
    bf16x8 alo = *(const bf16x8*)&hlo[(m0 + l15) * 40 + lg * 8];
    bf16x8 bhi = *(const bf16x8*)(W2hi + (size_t)(n0 + l15) * 32 + lg * 8);
    bf16x8 blo = *(const bf16x8*)(W2lo + (size_t)(n0 + l15) * 32 + lg * 8);
    acc = __builtin_amdgcn_mfma_f32_16x16x32_bf16(ahi, bhi, acc, 0, 0, 0);
    acc = __builtin_amdgcn_mfma_f32_16x16x32_bf16(ahi, blo, acc, 0, 0, 0);
    acc = __builtin_amdgcn_mfma_f32_16x16x32_bf16(alo, bhi, acc, 0, 0, 0);

    #pragma unroll
    for (int rg = 0; rg < 4; ++rg)
        pre[(size_t)(r0 + m0 + lg * 4 + rg) * 32 + n0 + l15] = acc[rg];
    float s  = (acc[0] + acc[1]) + (acc[2] + acc[3]);
    float sq = (acc[0] * acc[0] + acc[1] * acc[1]) + (acc[2] * acc[2] + acc[3] * acc[3]);
    s  += __shfl_xor(s, 16);  s  += __shfl_xor(s, 32);
    sq += __shfl_xor(sq, 16); sq += __shfl_xor(sq, 32);
    if (lg == 0) {
        int slot = (blockIdx.x * 2 + (q & 1)) * 32 + n0 + l15;
        st2p[slot] = s;
        st2p[32768 + slot] = sq;
    }
}

// ---------------- kernel 3: BN2 -> ReLU -> m -> 26-step LSTM, ping-pong dual groups ----------------
// 512 blocks x 256 thr; block = 32 rows = groups A(0..15), B(16..31); wave q owns u-quadrant.
// Interval = { MFMA(one group) || activation(other group) }; 2 barriers/step for 2 groups.
__global__ __launch_bounds__(256, 2) void k_lstm(
    const float* __restrict__ pre, const float* __restrict__ scsh2,
    const float* __restrict__ W3, const float* __restrict__ b3,
    const ushort* __restrict__ Wih_hi, const ushort* __restrict__ Wih_lo,
    const ushort* __restrict__ Wsum_hi, const ushort* __restrict__ Wsum_lo,
    const float* __restrict__ bsum, float* __restrict__ out)
{
    __shared__ __align__(16) ushort hhi[2][2][16][72];  // [group][buf][row][u]
    __shared__ __align__(16) ushort hlo[2][2][16][72];
    __shared__ float bn2sc[32], bn2sh[32];
    const int tid  = threadIdx.x;
    const int lane = tid & 63, l15 = lane & 15, lg = lane >> 4, q = tid >> 6;
    const int r0   = blockIdx.x * 32;

    if (tid < 32) { bn2sc[tid] = scsh2[tid]; bn2sh[tid] = scsh2[32 + tid]; }
    __syncthreads();

    // ---- MLP tail: m = relu(BN2(pre)) @ W3^T + b3 for 32 rows; write into buf 0 of each group
    {
        const int row = tid & 31, seg = tid >> 5;
        float h2[32];
        const float4* pr = (const float4*)(pre + (size_t)(r0 + row) * 32);
        #pragma unroll
        for (int j4 = 0; j4 < 8; ++j4) {
            float4 v = pr[j4];
            h2[j4 * 4 + 0] = v.x; h2[j4 * 4 + 1] = v.y;
            h2[j4 * 4 + 2] = v.z; h2[j4 * 4 + 3] = v.w;
        }
        #pragma unroll
        for (int j = 0; j < 32; ++j) h2[j] = fmaxf(fmaf(h2[j], bn2sc[j], bn2sh[j]), 0.f);
        #pragma unroll
        for (int uu = 0; uu < 8; ++uu) {
            int u = seg * 8 + uu;
            const float* w = W3 + u * 32;
            float a0 = 0.f, a1 = 0.f, a2 = 0.f, a3 = 0.f;
            #pragma unroll
            for (int k = 0; k < 32; k += 4) {
                a0 = fmaf(h2[k + 0], w[k + 0], a0);
                a1 = fmaf(h2[k + 1], w[k + 1], a1);
                a2 = fmaf(h2[k + 2], w[k + 2], a2);
                a3 = fmaf(h2[k + 3], w[k + 3], a3);
            }
            float m = b3[u] + ((a0 + a1) + (a2 + a3));
            ushort mh, ml; split_bf16(m, mh, ml);
            hhi[row >> 4][0][row & 15][u] = mh;
            hlo[row >> 4][0][row & 15][u] = ml;
        }
    }

    float bias[4];
    #pragma unroll
    for (int nt = 0; nt < 4; ++nt) bias[nt] = bsum[nt * 64 + q * 16 + l15];
    float cA[4] = {0.f, 0.f, 0.f, 0.f}, cB[4] = {0.f, 0.f, 0.f, 0.f};

    // step-invariant out-store base pointers (advance by SLOT*64 per store)
    float* obA[4];
    float* obB[4];
    #pragma unroll
    for (int rg = 0; rg < 4; ++rg) {
        obA[rg] = out + (size_t)(r0 + lg * 4 + rg) * 1600 + (q * 16 + l15);
        obB[rg] = out + (size_t)(r0 + 16 + lg * 4 + rg) * 1600 + (q * 16 + l15);
    }

    bf16x8 Bhi[4][2], Blo[4][2];
    const size_t wofs = (size_t)(q * 16 + l15) * 64 + lg * 8;
    #pragma unroll
    for (int nt = 0; nt < 4; ++nt)
        #pragma unroll
        for (int kt = 0; kt < 2; ++kt) {
            Bhi[nt][kt] = *(const bf16x8*)(Wih_hi + (size_t)nt * 4096 + wofs + kt * 32);
            Blo[nt][kt] = *(const bf16x8*)(Wih_lo + (size_t)nt * 4096 + wofs + kt * 32);
        }
    __syncthreads();

#define MFMA_GATES(ACC, G, BUF)                                                  \
    {                                                                            \
        _Pragma("unroll")                                                        \
        for (int nt = 0; nt < 4; ++nt)                                           \
            ACC[nt] = (f32x4){bias[nt], bias[nt], bias[nt], bias[nt]};           \
        _Pragma("unroll")                                                        \
        for (int kt = 0; kt < 2; ++kt) {                                         \
            bf16x8 ahi = *(const bf16x8*)&hhi[G][BUF][l15][kt * 32 + lg * 8];    \
            bf16x8 alo = *(const bf16x8*)&hlo[G][BUF][l15][kt * 32 + lg * 8];    \
            _Pragma("unroll")                                                    \
            for (int nt = 0; nt < 4; ++nt) {                                     \
                ACC[nt] = __builtin_amdgcn_mfma_f32_16x16x32_bf16(ahi, Bhi[nt][kt], ACC[nt], 0, 0, 0); \
                ACC[nt] = __builtin_amdgcn_mfma_f32_16x16x32_bf16(ahi, Blo[nt][kt], ACC[nt], 0, 0, 0); \
                ACC[nt] = __builtin_amdgcn_mfma_f32_16x16x32_bf16(alo, Bhi[nt][kt], ACC[nt], 0, 0, 0); \
            }                                                                    \
        }                                                                        \
    }

    // exp2-domain activations: i,f,o scaled by log2e; g by 2log2e (baked into W/bsum).
#define ACT(ACC, C, G, WBUF, OB, SLOT, WRLDS)                                    \
    {                                                                            \
        const int u = q * 16 + l15;                                              \
        _Pragma("unroll")                                                        \
        for (int rg = 0; rg < 4; ++rg) {                                         \
            int row = lg * 4 + rg;                                               \
            float iv = ACC[0][rg], fv = ACC[1][rg];                              \
            float gv = ACC[2][rg], ov = ACC[3][rg];                              \
            float Af = __builtin_amdgcn_exp2f(-fv);                              \
            float Ai = __builtin_amdgcn_exp2f(-iv);                              \
            float Bg = __builtin_amdgcn_exp2f(gv);                               \
            float sig = (Bg - 1.f) * rcp_f((1.f + Ai) * (Bg + 1.f));             \
            float cc = C[rg] * rcp_f(1.f + Af) + sig;                            \
            C[rg] = cc;                                                          \
            float Ao = __builtin_amdgcn_exp2f(-ov);                              \
            float C2 = __builtin_amdgcn_exp2f(cc * K2);                          \
            float hn = (C2 - 1.f) * rcp_f((1.f + Ao) * (C2 + 1.f));              \
            if (WRLDS) {                                                         \
                ushort hh, hl; split_bf16(hn, hh, hl);                           \
                hhi[G][WBUF][row][u] = hh;                                       \
                hlo[G][WBUF][row][u] = hl;                                       \
            }                                                                    \
            if ((SLOT) >= 0)                                                     \
                OB[rg][(size_t)(SLOT) * 64] = hn;                                \
        }                                                                        \
    }

    f32x4 accA[4], accB[4];

    // ---- prologue: step 0 (input m, weights Wih)
    MFMA_GATES(accA, 0, 0);
    MFMA_GATES(accB, 1, 0);
    // switch resident weights to Wsum for self-feed steps (loads overlap act below)
    #pragma unroll
    for (int nt = 0; nt < 4; ++nt)
        #pragma unroll
        for (int kt = 0; kt < 2; ++kt) {
            Bhi[nt][kt] = *(const bf16x8*)(Wsum_hi + (size_t)nt * 4096 + wofs + kt * 32);
            Blo[nt][kt] = *(const bf16x8*)(Wsum_lo + (size_t)nt * 4096 + wofs + kt * 32);
        }
    ACT(accA, cA, 0, 1, obA, -1, 1);     // h_A^1 -> bufA[1], no output
    __syncthreads();

    // ---- steady ping-pong: 2 intervals per step
    #pragma unroll 1
    for (int s = 1; s <= 25; ++s) {
        const int rb = s & 1, wb = rb ^ 1;
        MFMA_GATES(accA, 0, rb);               // gates_A(s) from h_A^s
        ACT(accB, cB, 1, rb, obB, s - 2, 1);   // h_B^s -> bufB[rb], out slot s-2
        __syncthreads();
        MFMA_GATES(accB, 1, rb);               // gates_B(s) from h_B^s
        ACT(accA, cA, 0, wb, obA, s - 1, 1);   // h_A^{s+1} -> bufA[wb], out slot s-1
        __syncthreads();
    }
    // ---- epilogue: finish group B step 25
    ACT(accB, cB, 1, 0, obB, 24, 0);

#undef MFMA_GATES
#undef ACT
}

extern "C" void kernel_launch(void* const* d_in, const int* in_sizes, int n_in,
                              void* d_out, int out_size, void* d_ws, size_t ws_size,
                              hipStream_t stream) {
    const float* x0   = (const float*)d_in[0];
    const float* x1   = (const float*)d_in[1];
    const float* x2   = (const float*)d_in[2];
    const float* W1   = (const float*)d_in[3];
    const float* b1   = (const float*)d_in[4];
    const float* g1   = (const float*)d_in[5];
    const float* be1  = (const float*)d_in[6];
    const float* W2   = (const float*)d_in[7];
    const float* b2   = (const float*)d_in[8];
    const float* g2   = (const float*)d_in[9];
    const float* be2  = (const float*)d_in[10];
    const float* W3   = (const float*)d_in[11];
    const float* b3   = (const float*)d_in[12];
    const float* Wih  = (const float*)d_in[13];
    const float* Whh  = (const float*)d_in[14];
    const float* bih  = (const float*)d_in[15];
    const float* bhh  = (const float*)d_in[16];

    float* ws    = (float*)d_ws;
    float* pre   = ws;                   // 524288 floats (pre1, then pre2 in-place)
    float* st1p  = ws + 524288;          // 65536
    float* st2p  = ws + 589824;          // 65536
    float* scsh1 = ws + 655360;          // 64
    float* scsh2 = ws + 655424;          // 64
    float* bsum  = ws + 655488;          // 256
    ushort* ub   = (ushort*)(ws + 655744);
    ushort* Wih_hi  = ub;                // 16384
    ushort* Wih_lo  = ub + 16384;
    ushort* Wsum_hi = ub + 32768;
    ushort* Wsum_lo = ub + 49152;
    ushort* W1hi    = ub + 65536;        // 12288
    ushort* W1lo    = ub + 77824;
    ushort* W2hi    = ub + 90112;        // 1024
    ushort* W2lo    = ub + 91136;        // end 92160

    hipLaunchKernelGGL(k_prep, dim3(64), dim3(256), 0, stream,
                       Wih, Whh, bih, bhh, W1, W2,
                       Wih_hi, Wih_lo, Wsum_hi, Wsum_lo, W1hi, W1lo, W2hi, W2lo, bsum);
    hipLaunchKernelGGL(k_mlp1, dim3(512), dim3(256), 0, stream,
                       x0, x1, x2, W1hi, W1lo, b1, pre, st1p);
    hipLaunchKernelGGL(k_red, dim3(32), dim3(256), 0, stream, st1p, g1, be1, scsh1);
    hipLaunchKernelGGL(k_mlp2, dim3(512), dim3(256), 0, stream,
                       pre, scsh1, W2hi, W2lo, b2, st2p);
    hipLaunchKernelGGL(k_red, dim3(32), dim3(256), 0, stream, st2p, g2, be2, scsh2);
    hipLaunchKernelGGL(k_lstm, dim3(512), dim3(256), 0, stream,
                       pre, scsh2, W3, b3,
                       Wih_hi, Wih_lo, Wsum_hi, Wsum_lo, bsum, (float*)d_out);
}